// Round 4
// baseline (420.616 us; speedup 1.0000x reference)
//
#include <hip/hip_runtime.h>
#include <math.h>

// 4 lanes ("quad") per query point.
//  lane l in [0,4): handles corner pair (iy,ix) = (l>>1, l&1) -> 4 corners,
//  16x dwordx4 gathers, partial feat[16]; quad butterfly reduce via shfl_xor;
//  MLP 16->64 sliced by j across the quad; o reduce via shfl_xor; lanes 0-2
//  write the 3 outputs.
// grid: [64][64][32][32][16] fp32 (256 MB)
__global__ __launch_bounds__(256, 6) void gridnet_quad(
    const float* __restrict__ x,
    const float* __restrict__ grid,
    const float* __restrict__ w1,   // [16][64]
    const float* __restrict__ b1,   // [64]
    const float* __restrict__ w2,   // [64][3]
    const float* __restrict__ b2,   // [3]
    float* __restrict__ out,        // [N][3]
    int N)
{
    __shared__ float w1s[16 * 64];
    __shared__ float b1s[64];
    __shared__ float w2s[64 * 3];
    __shared__ float b2s[4];

    const int t = threadIdx.x;
    for (int i = t; i < 1024; i += 256) w1s[i] = w1[i];
    if (t < 64)  b1s[t] = b1[t];
    if (t < 192) w2s[t] = w2[t];
    if (t < 4)   b2s[t] = (t < 3) ? b2[t] : 0.0f;
    __syncthreads();

    const int lane = t & 3;
    const int q    = t >> 2;
    const int p    = blockIdx.x * 64 + q;
    if (p >= N) return;   // no barriers below this point

    const float4 xv = reinterpret_cast<const float4*>(x)[p];

    // Coordinate -> grid index space. BIT-EXACT vs reference f32 sequence:
    // (x - lo) / span * count; lo/span from f64 python scalars cast to f32.
    // Keep the divide (no reciprocal folding) — trunc decisions at cell
    // boundaries are discrete.
    const float lo1 = (float)(-M_PI);
    const float sp0 = (float)(M_PI);
    const float sp1 = (float)(2.0 * M_PI);
    const float lo2 = (float)(0.5 * M_PI);
    const float sp2 = (float)(0.85 * M_PI - 0.5 * M_PI);
    const float lo3 = (float)(-0.85 * M_PI);
    const float sp3 = (float)(-0.5 * M_PI - (-0.85 * M_PI));

    const float c0 = (xv.x - 0.0f) / sp0 * 63.0f;
    const float c1 = (xv.y - lo1) / sp1 * 63.0f;
    const float c2 = (xv.z - lo2) / sp2 * 31.0f;
    const float c3 = (xv.w - lo3) / sp3 * 31.0f;

    const int tlx = (int)c0;
    const int tly = (int)c1;
    const int tlz = (int)c2;
    const int tlw = (int)c3;

    const float xf = c0 - (float)tlx;
    const float yf = c1 - (float)tly;
    const float zf = c2 - (float)tlz;
    const float wf = c3 - (float)tlw;

    const int brx = min(tlx + 1, 63);
    const int bry = min(tly + 1, 63);
    const int brz = min(tlz + 1, 31);
    const int brw = min(tlw + 1, 31);

    const float wz0 = 1.0f - zf, wz1 = zf;
    const float ww0 = 1.0f - wf, ww1 = wf;

    // this lane's (iy,ix)
    const int  iy  = lane >> 1;
    const int  ix  = lane & 1;
    const int  ay  = iy ? bry : tly;
    const int  ax  = ix ? brx : tlx;
    const float wyl = iy ? yf : (1.0f - yf);
    const float wxl = ix ? xf : (1.0f - xf);
    const float wbase = wxl * wyl;

    // (z,w) sub-weights; reference quirk: for iy==1 the (z0,w1) and (z1,w0)
    // slots are swapped.
    const float s00  = wz0 * ww0;
    const float s11  = wz1 * ww1;
    const float s01n = wz0 * ww1;
    const float s10n = wz1 * ww0;
    const float s01 = iy ? s10n : s01n;
    const float s10 = iy ? s01n : s10n;

    const int base = (ay * 64 + ax) * 32;
    const int idx00 = (base + tlz) * 32 + tlw;
    const int idx01 = (base + tlz) * 32 + brw;
    const int idx10 = (base + brz) * 32 + tlw;
    const int idx11 = (base + brz) * 32 + brw;

    const float ws[4]  = {wbase * s00, wbase * s01, wbase * s10, wbase * s11};
    const int   idxs[4] = {idx00, idx01, idx10, idx11};

    float feat[16];
    #pragma unroll
    for (int f = 0; f < 16; ++f) feat[f] = 0.0f;

    #pragma unroll
    for (int c = 0; c < 4; ++c) {
        const float4* p4 = reinterpret_cast<const float4*>(
            grid + (size_t)idxs[c] * 16);
        const float4 v0 = p4[0];
        const float4 v1 = p4[1];
        const float4 v2 = p4[2];
        const float4 v3 = p4[3];
        const float w = ws[c];
        feat[0]  += w * v0.x;  feat[1]  += w * v0.y;
        feat[2]  += w * v0.z;  feat[3]  += w * v0.w;
        feat[4]  += w * v1.x;  feat[5]  += w * v1.y;
        feat[6]  += w * v1.z;  feat[7]  += w * v1.w;
        feat[8]  += w * v2.x;  feat[9]  += w * v2.y;
        feat[10] += w * v2.z;  feat[11] += w * v2.w;
        feat[12] += w * v3.x;  feat[13] += w * v3.y;
        feat[14] += w * v3.z;  feat[15] += w * v3.w;
    }

    // reduce feat across the quad (xor 1, xor 2 stay inside the quad)
    #pragma unroll
    for (int f = 0; f < 16; ++f) {
        feat[f] += __shfl_xor(feat[f], 1);
        feat[f] += __shfl_xor(feat[f], 2);
    }

    // MLP sliced by j: lane handles j4 groups {lane, lane+4, lane+8, lane+12}
    float o0 = 0.0f, o1 = 0.0f, o2 = 0.0f;
    #pragma unroll
    for (int g = 0; g < 4; ++g) {
        const int j4 = lane + 4 * g;
        float4 h = reinterpret_cast<const float4*>(b1s)[j4];
        #pragma unroll
        for (int i = 0; i < 16; ++i) {
            const float4 wv = reinterpret_cast<const float4*>(w1s)[i * 16 + j4];
            h.x += feat[i] * wv.x;
            h.y += feat[i] * wv.y;
            h.z += feat[i] * wv.z;
            h.w += feat[i] * wv.w;
        }
        const float hx = (h.x >= 0.0f) ? h.x : 0.01f * h.x;
        const float hy = (h.y >= 0.0f) ? h.y : 0.01f * h.y;
        const float hz = (h.z >= 0.0f) ? h.z : 0.01f * h.z;
        const float hw = (h.w >= 0.0f) ? h.w : 0.01f * h.w;
        const float* w2p = w2s + j4 * 12;
        o0 += hx * w2p[0] + hy * w2p[3] + hz * w2p[6] + hw * w2p[9];
        o1 += hx * w2p[1] + hy * w2p[4] + hz * w2p[7] + hw * w2p[10];
        o2 += hx * w2p[2] + hy * w2p[5] + hz * w2p[8] + hw * w2p[11];
    }

    // reduce the 3 outputs across the quad
    o0 += __shfl_xor(o0, 1);  o0 += __shfl_xor(o0, 2);
    o1 += __shfl_xor(o1, 1);  o1 += __shfl_xor(o1, 2);
    o2 += __shfl_xor(o2, 1);  o2 += __shfl_xor(o2, 2);

    const float osel = (lane == 0) ? o0 : ((lane == 1) ? o1 : o2);
    const float ob   = osel + b2s[lane];   // lane 3 computes garbage, never writes
    const float r    = 255.0f / (1.0f + expf(-ob));
    if (lane < 3) out[(size_t)p * 3 + lane] = r;
}

extern "C" void kernel_launch(void* const* d_in, const int* in_sizes, int n_in,
                              void* d_out, int out_size, void* d_ws, size_t ws_size,
                              hipStream_t stream) {
    const float* x    = (const float*)d_in[0];
    const float* grid = (const float*)d_in[1];
    const float* w1   = (const float*)d_in[2];
    const float* b1   = (const float*)d_in[3];
    const float* w2   = (const float*)d_in[4];
    const float* b2   = (const float*)d_in[5];
    float* out = (float*)d_out;

    const int N = in_sizes[0] / 4;           // x is [N,4]
    const int blocks = (N + 63) / 64;        // 64 points per 256-thread block
    gridnet_quad<<<blocks, 256, 0, stream>>>(x, grid, w1, b1, w2, b2, out, N);
}

// Round 5
// 356.989 us; speedup vs baseline: 1.1782x; 1.1782x over previous
//
#include <hip/hip_runtime.h>
#include <math.h>

// Pipeline: bin points by grid cell -> process in cell order for L2 locality.
//   ws layout: xs (N float4, 16MB) | idx (N u32, 4MB) | hist (2M u32, 8MB)
//              | partial (2048 u32)
//   key = (((ty*64+tx)*32+tz)*16 + (tw>>1))  in [0, 2^21)
// Main kernel is the round-3 bit-exact body (1 thread/point).

#define NBUCKET (1u << 21)
#define SCAN_BLOCKS 2048   // NBUCKET / 1024

__device__ __forceinline__ int point_key(const float4 xv) {
    // fast binning — affects only performance, never output values
    const float c0 = xv.x * (63.0f / (float)M_PI);
    const float c1 = (xv.y + (float)M_PI) * (63.0f / (float)(2.0 * M_PI));
    const float c2 = (xv.z - (float)(0.5 * M_PI)) * (31.0f / (float)(0.35 * M_PI));
    const float c3 = (xv.w + (float)(0.85 * M_PI)) * (31.0f / (float)(0.35 * M_PI));
    int tx = min(max((int)c0, 0), 63);
    int ty = min(max((int)c1, 0), 63);
    int tz = min(max((int)c2, 0), 31);
    int tw = min(max((int)c3, 0), 31);
    return ((ty * 64 + tx) * 32 + tz) * 16 + (tw >> 1);
}

__global__ __launch_bounds__(1024) void k_zero(unsigned* __restrict__ hist) {
    hist[blockIdx.x * 1024 + threadIdx.x] = 0u;
}

__global__ __launch_bounds__(256) void k_hist(const float4* __restrict__ x,
                                              unsigned* __restrict__ hist, int N) {
    const int p = blockIdx.x * 256 + threadIdx.x;
    if (p >= N) return;
    atomicAdd(&hist[point_key(x[p])], 1u);
}

__global__ __launch_bounds__(1024) void k_scanA(unsigned* __restrict__ data,
                                                unsigned* __restrict__ partial) {
    __shared__ unsigned s[1024];
    const int t = threadIdx.x;
    const int base = blockIdx.x * 1024;
    const unsigned v = data[base + t];
    s[t] = v;
    __syncthreads();
    #pragma unroll
    for (int off = 1; off < 1024; off <<= 1) {
        const unsigned add = (t >= off) ? s[t - off] : 0u;
        __syncthreads();
        s[t] += add;
        __syncthreads();
    }
    data[base + t] = (t == 0) ? 0u : s[t - 1];           // exclusive
    if (t == 1023) partial[blockIdx.x] = s[1023];        // block total
}

__global__ __launch_bounds__(1024) void k_scanB(unsigned* __restrict__ partial) {
    __shared__ unsigned s[1024];
    const int t = threadIdx.x;
    const unsigned v0 = partial[2 * t];
    const unsigned v1 = partial[2 * t + 1];
    s[t] = v0 + v1;
    __syncthreads();
    #pragma unroll
    for (int off = 1; off < 1024; off <<= 1) {
        const unsigned add = (t >= off) ? s[t - off] : 0u;
        __syncthreads();
        s[t] += add;
        __syncthreads();
    }
    const unsigned exc = (t == 0) ? 0u : s[t - 1];
    partial[2 * t] = exc;
    partial[2 * t + 1] = exc + v0;
}

__global__ __launch_bounds__(1024) void k_scanC(unsigned* __restrict__ data,
                                                const unsigned* __restrict__ partial) {
    data[blockIdx.x * 1024 + threadIdx.x] += partial[blockIdx.x];
}

__global__ __launch_bounds__(256) void k_scatter(const float4* __restrict__ x,
                                                 unsigned* __restrict__ offsets,
                                                 float4* __restrict__ xs,
                                                 unsigned* __restrict__ idx, int N) {
    const int p = blockIdx.x * 256 + threadIdx.x;
    if (p >= N) return;
    const float4 xv = x[p];
    const unsigned slot = atomicAdd(&offsets[point_key(xv)], 1u);
    xs[slot] = xv;
    idx[slot] = p;
}

// ---------------- main compute (bit-exact round-3 body) ----------------
template <bool SORTED>
__global__ __launch_bounds__(256) void gridnet_main(
    const float4* __restrict__ xs,       // sorted x (or raw x if !SORTED)
    const unsigned* __restrict__ idx,    // sorted->original (unused if !SORTED)
    const float* __restrict__ grid,
    const float* __restrict__ w1, const float* __restrict__ b1,
    const float* __restrict__ w2, const float* __restrict__ b2,
    float* __restrict__ out, int N, int nblk)
{
    __shared__ float w1s[16 * 64];
    __shared__ float b1s[64];
    __shared__ float w2s[64 * 3];
    __shared__ float b2s[4];

    const int t = threadIdx.x;
    for (int i = t; i < 1024; i += 256) w1s[i] = w1[i];
    if (t < 64)  b1s[t] = b1[t];
    if (t < 192) w2s[t] = w2[t];
    if (t < 3)   b2s[t] = b2[t];
    __syncthreads();

    // XCD-chunked block order: XCD k gets a contiguous range of sorted slots
    int b = blockIdx.x;
    if (SORTED && (nblk & 7) == 0)
        b = (blockIdx.x & 7) * (nblk >> 3) + (blockIdx.x >> 3);

    const int i = b * 256 + t;
    if (i >= N) return;

    const float4 xv = xs[i];
    const int p = SORTED ? (int)idx[i] : i;

    // BIT-EXACT coordinate path: (x - lo) / span * count, f64 consts cast
    // to f32, divide preserved (trunc decisions at cell edges are discrete).
    const float lo1 = (float)(-M_PI);
    const float sp0 = (float)(M_PI);
    const float sp1 = (float)(2.0 * M_PI);
    const float lo2 = (float)(0.5 * M_PI);
    const float sp2 = (float)(0.85 * M_PI - 0.5 * M_PI);
    const float lo3 = (float)(-0.85 * M_PI);
    const float sp3 = (float)(-0.5 * M_PI - (-0.85 * M_PI));

    const float c0 = (xv.x - 0.0f) / sp0 * 63.0f;
    const float c1 = (xv.y - lo1) / sp1 * 63.0f;
    const float c2 = (xv.z - lo2) / sp2 * 31.0f;
    const float c3 = (xv.w - lo3) / sp3 * 31.0f;

    const int tlx = (int)c0;
    const int tly = (int)c1;
    const int tlz = (int)c2;
    const int tlw = (int)c3;

    const float xf = c0 - (float)tlx;
    const float yf = c1 - (float)tly;
    const float zf = c2 - (float)tlz;
    const float wf = c3 - (float)tlw;

    const int brx = min(tlx + 1, 63);
    const int bry = min(tly + 1, 63);
    const int brz = min(tlz + 1, 31);
    const int brw = min(tlw + 1, 31);

    const float wx0 = 1.0f - xf, wx1 = xf;
    const float wy0 = 1.0f - yf, wy1 = yf;
    const float wz0 = 1.0f - zf, wz1 = zf;
    const float ww0 = 1.0f - wf, ww1 = wf;

    // reference quirk: for iy==1 the (z0,w1)/(z1,w0) weights are swapped
    float cw[2][2][2];
    cw[0][0][0] = wy0 * wz0 * ww0;
    cw[0][0][1] = wy0 * wz0 * ww1;
    cw[0][1][0] = wy0 * wz1 * ww0;
    cw[0][1][1] = wy0 * wz1 * ww1;
    cw[1][0][0] = wy1 * wz0 * ww0;
    cw[1][0][1] = wy1 * wz1 * ww0;   // swapped
    cw[1][1][0] = wy1 * wz0 * ww1;   // swapped
    cw[1][1][1] = wy1 * wz1 * ww1;

    const float wxv[2] = {wx0, wx1};
    const int axv[2] = {tlx, brx};
    const int ayv[2] = {tly, bry};
    const int azv[2] = {tlz, brz};
    const int awv[2] = {tlw, brw};

    float feat[16];
    #pragma unroll
    for (int f = 0; f < 16; ++f) feat[f] = 0.0f;

    #pragma unroll
    for (int iy = 0; iy < 2; ++iy) {
        #pragma unroll
        for (int ix = 0; ix < 2; ++ix) {
            const int base1 = (ayv[iy] * 64 + axv[ix]) * 32;
            const float wyx = wxv[ix];
            #pragma unroll
            for (int iz = 0; iz < 2; ++iz) {
                const int base0 = (base1 + azv[iz]) * 32;
                #pragma unroll
                for (int iw = 0; iw < 2; ++iw) {
                    const float w = wyx * cw[iy][iz][iw];
                    const float4* p4 = reinterpret_cast<const float4*>(
                        grid + (size_t)(base0 + awv[iw]) * 16);
                    const float4 v0 = p4[0];
                    const float4 v1 = p4[1];
                    const float4 v2 = p4[2];
                    const float4 v3 = p4[3];
                    feat[0]  += w * v0.x;  feat[1]  += w * v0.y;
                    feat[2]  += w * v0.z;  feat[3]  += w * v0.w;
                    feat[4]  += w * v1.x;  feat[5]  += w * v1.y;
                    feat[6]  += w * v1.z;  feat[7]  += w * v1.w;
                    feat[8]  += w * v2.x;  feat[9]  += w * v2.y;
                    feat[10] += w * v2.z;  feat[11] += w * v2.w;
                    feat[12] += w * v3.x;  feat[13] += w * v3.y;
                    feat[14] += w * v3.z;  feat[15] += w * v3.w;
                }
            }
        }
    }

    float o0 = b2s[0];
    float o1 = b2s[1];
    float o2 = b2s[2];

    #pragma unroll
    for (int j4 = 0; j4 < 16; ++j4) {
        float4 h = reinterpret_cast<const float4*>(b1s)[j4];
        #pragma unroll
        for (int i2 = 0; i2 < 16; ++i2) {
            const float4 wv = reinterpret_cast<const float4*>(w1s)[i2 * 16 + j4];
            h.x += feat[i2] * wv.x;
            h.y += feat[i2] * wv.y;
            h.z += feat[i2] * wv.z;
            h.w += feat[i2] * wv.w;
        }
        const float hx = (h.x >= 0.0f) ? h.x : 0.01f * h.x;
        const float hy = (h.y >= 0.0f) ? h.y : 0.01f * h.y;
        const float hz = (h.z >= 0.0f) ? h.z : 0.01f * h.z;
        const float hw = (h.w >= 0.0f) ? h.w : 0.01f * h.w;
        const float* w2p = w2s + j4 * 12;
        o0 += hx * w2p[0] + hy * w2p[3] + hz * w2p[6] + hw * w2p[9];
        o1 += hx * w2p[1] + hy * w2p[4] + hz * w2p[7] + hw * w2p[10];
        o2 += hx * w2p[2] + hy * w2p[5] + hz * w2p[8] + hw * w2p[11];
    }

    const float r0 = 255.0f / (1.0f + expf(-o0));
    const float r1 = 255.0f / (1.0f + expf(-o1));
    const float r2 = 255.0f / (1.0f + expf(-o2));

    float* op = out + (size_t)p * 3;
    op[0] = r0;
    op[1] = r1;
    op[2] = r2;
}

extern "C" void kernel_launch(void* const* d_in, const int* in_sizes, int n_in,
                              void* d_out, int out_size, void* d_ws, size_t ws_size,
                              hipStream_t stream) {
    const float* x    = (const float*)d_in[0];
    const float* grid = (const float*)d_in[1];
    const float* w1   = (const float*)d_in[2];
    const float* b1   = (const float*)d_in[3];
    const float* w2   = (const float*)d_in[4];
    const float* b2   = (const float*)d_in[5];
    float* out = (float*)d_out;

    const int N = in_sizes[0] / 4;               // x is [N,4]
    const int nblk = (N + 255) / 256;

    // ws layout
    const size_t xs_bytes   = (size_t)N * 16;
    const size_t idx_bytes  = (size_t)N * 4;
    const size_t hist_bytes = (size_t)NBUCKET * 4;
    const size_t part_bytes = (size_t)SCAN_BLOCKS * 4;
    const size_t need = xs_bytes + idx_bytes + hist_bytes + part_bytes;

    if (ws_size >= need && N == SCAN_BLOCKS * 512) {
        char* ws = (char*)d_ws;
        float4*   xs      = (float4*)ws;
        unsigned* idx     = (unsigned*)(ws + xs_bytes);
        unsigned* hist    = (unsigned*)(ws + xs_bytes + idx_bytes);
        unsigned* partial = (unsigned*)(ws + xs_bytes + idx_bytes + hist_bytes);
        const float4* x4 = (const float4*)x;

        k_zero   <<<NBUCKET / 1024, 1024, 0, stream>>>(hist);
        k_hist   <<<nblk, 256, 0, stream>>>(x4, hist, N);
        k_scanA  <<<SCAN_BLOCKS, 1024, 0, stream>>>(hist, partial);
        k_scanB  <<<1, 1024, 0, stream>>>(partial);
        k_scanC  <<<SCAN_BLOCKS, 1024, 0, stream>>>(hist, partial);
        k_scatter<<<nblk, 256, 0, stream>>>(x4, hist, xs, idx, N);
        gridnet_main<true><<<nblk, 256, 0, stream>>>(
            xs, idx, grid, w1, b1, w2, b2, out, N, nblk);
    } else {
        // fallback: direct, unsorted
        gridnet_main<false><<<nblk, 256, 0, stream>>>(
            (const float4*)x, nullptr, grid, w1, b1, w2, b2, out, N, nblk);
    }
}

// Round 6
// 299.421 us; speedup vs baseline: 1.4048x; 1.1923x over previous
//
#include <hip/hip_runtime.h>
#include <math.h>

// Pipeline: bin points by (y,x,z) grid cell -> process in cell order.
// Main kernel: 256 threads / 256 points per block.
//   Phase 1 (gather): 4 lanes per point, lane = 16B chunk of each 64B corner
//     line -> every wave load instruction consumes 16 full cache lines.
//     Lane l accumulates feat[4l..4l+3] (bit-exact corner order) -> LDS.
//   Phase 2 (MLP GEMM): thread = (8-point group, 8-j group) tile; h[8][8] in
//     regs; o reduced across j-groups via in-wave shfl_xor butterfly.

#define NBUCKET 131072          // 64*64*32 (y,x,z)
#define SCAN_BLOCKS 128         // NBUCKET / 1024
#define FEAT_PITCH 260          // 16B-aligned rows, bank-stagger

__device__ __forceinline__ int point_key(const float4 xv) {
    // fast binning — performance only, never affects output values
    const float c0 = xv.x * (63.0f / (float)M_PI);
    const float c1 = (xv.y + (float)M_PI) * (63.0f / (float)(2.0 * M_PI));
    const float c2 = (xv.z - (float)(0.5 * M_PI)) * (31.0f / (float)(0.35 * M_PI));
    int tx = min(max((int)c0, 0), 63);
    int ty = min(max((int)c1, 0), 63);
    int tz = min(max((int)c2, 0), 31);
    return (ty * 64 + tx) * 32 + tz;
}

__global__ __launch_bounds__(1024) void k_zero(unsigned* __restrict__ hist) {
    hist[blockIdx.x * 1024 + threadIdx.x] = 0u;
}

__global__ __launch_bounds__(256) void k_hist(const float4* __restrict__ x,
                                              unsigned* __restrict__ hist, int N) {
    const int p = blockIdx.x * 256 + threadIdx.x;
    if (p >= N) return;
    atomicAdd(&hist[point_key(x[p])], 1u);
}

__global__ __launch_bounds__(1024) void k_scanA(unsigned* __restrict__ data,
                                                unsigned* __restrict__ partial) {
    __shared__ unsigned s[1024];
    const int t = threadIdx.x;
    const int base = blockIdx.x * 1024;
    const unsigned v = data[base + t];
    s[t] = v;
    __syncthreads();
    #pragma unroll
    for (int off = 1; off < 1024; off <<= 1) {
        const unsigned add = (t >= off) ? s[t - off] : 0u;
        __syncthreads();
        s[t] += add;
        __syncthreads();
    }
    data[base + t] = (t == 0) ? 0u : s[t - 1];           // exclusive
    if (t == 1023) partial[blockIdx.x] = s[1023];
}

__global__ __launch_bounds__(SCAN_BLOCKS) void k_scanB(unsigned* __restrict__ partial) {
    __shared__ unsigned s[SCAN_BLOCKS];
    const int t = threadIdx.x;
    const unsigned v = partial[t];
    s[t] = v;
    __syncthreads();
    #pragma unroll
    for (int off = 1; off < SCAN_BLOCKS; off <<= 1) {
        const unsigned add = (t >= off) ? s[t - off] : 0u;
        __syncthreads();
        s[t] += add;
        __syncthreads();
    }
    partial[t] = s[t] - v;                                // exclusive
}

__global__ __launch_bounds__(1024) void k_scanC(unsigned* __restrict__ data,
                                                const unsigned* __restrict__ partial) {
    data[blockIdx.x * 1024 + threadIdx.x] += partial[blockIdx.x];
}

__global__ __launch_bounds__(256) void k_scatter(const float4* __restrict__ x,
                                                 unsigned* __restrict__ offsets,
                                                 float4* __restrict__ xs,
                                                 unsigned* __restrict__ idx, int N) {
    const int p = blockIdx.x * 256 + threadIdx.x;
    if (p >= N) return;
    const float4 xv = x[p];
    const unsigned slot = atomicAdd(&offsets[point_key(xv)], 1u);
    xs[slot] = xv;
    idx[slot] = p;
}

// ---------------- main compute ----------------
template <bool SORTED>
__global__ __launch_bounds__(256, 4) void gridnet_main(
    const float4* __restrict__ xs,
    const unsigned* __restrict__ idx,
    const float* __restrict__ grid,
    const float* __restrict__ w1, const float* __restrict__ b1,
    const float* __restrict__ w2, const float* __restrict__ b2,
    float* __restrict__ out, int N, int nblk)
{
    __shared__ float w1s[1024];                 // [16][64]
    __shared__ float featS[16 * FEAT_PITCH];    // [i][pt], pitch 260
    __shared__ float b1s[64];
    __shared__ float w2s[192];                  // [64][3]
    __shared__ float b2s[4];

    const int t = threadIdx.x;
    for (int i = t; i < 1024; i += 256) w1s[i] = w1[i];
    if (t < 64)  b1s[t] = b1[t];
    if (t < 192) w2s[t] = w2[t];
    if (t < 3)   b2s[t] = b2[t];

    int b = blockIdx.x;
    if ((nblk & 7) == 0)                        // XCD-chunked order
        b = (blockIdx.x & 7) * (nblk >> 3) + (blockIdx.x >> 3);
    const int base = b * 256;

    // BIT-EXACT coordinate constants (f64 python scalars cast to f32)
    const float lo1 = (float)(-M_PI);
    const float sp0 = (float)(M_PI);
    const float sp1 = (float)(2.0 * M_PI);
    const float lo2 = (float)(0.5 * M_PI);
    const float sp2 = (float)(0.85 * M_PI - 0.5 * M_PI);
    const float lo3 = (float)(-0.85 * M_PI);
    const float sp3 = (float)(-0.5 * M_PI - (-0.85 * M_PI));

    // ---- phase 1: gather. quad qb = t>>2 handles pts qb+64k, lane = chunk.
    const int l  = t & 3;
    const int qb = t >> 2;

    #pragma unroll
    for (int k = 0; k < 4; ++k) {
        const int pl = qb + 64 * k;            // local point
        const int gp = base + pl;
        float4 acc = make_float4(0.f, 0.f, 0.f, 0.f);
        if (gp < N) {
            const float4 xv = xs[gp];

            const float c0 = (xv.x - 0.0f) / sp0 * 63.0f;
            const float c1 = (xv.y - lo1) / sp1 * 63.0f;
            const float c2 = (xv.z - lo2) / sp2 * 31.0f;
            const float c3 = (xv.w - lo3) / sp3 * 31.0f;

            const int tlx = (int)c0;
            const int tly = (int)c1;
            const int tlz = (int)c2;
            const int tlw = (int)c3;

            const float xf = c0 - (float)tlx;
            const float yf = c1 - (float)tly;
            const float zf = c2 - (float)tlz;
            const float wf = c3 - (float)tlw;

            const int brx = min(tlx + 1, 63);
            const int bry = min(tly + 1, 63);
            const int brz = min(tlz + 1, 31);
            const int brw = min(tlw + 1, 31);

            const float wx0 = 1.0f - xf, wx1 = xf;
            const float wy0 = 1.0f - yf, wy1 = yf;
            const float wz0 = 1.0f - zf, wz1 = zf;
            const float ww0 = 1.0f - wf, ww1 = wf;

            // reference quirk: iy==1 has (z0,w1)/(z1,w0) swapped
            float cw[2][2][2];
            cw[0][0][0] = wy0 * wz0 * ww0;
            cw[0][0][1] = wy0 * wz0 * ww1;
            cw[0][1][0] = wy0 * wz1 * ww0;
            cw[0][1][1] = wy0 * wz1 * ww1;
            cw[1][0][0] = wy1 * wz0 * ww0;
            cw[1][0][1] = wy1 * wz1 * ww0;   // swapped
            cw[1][1][0] = wy1 * wz0 * ww1;   // swapped
            cw[1][1][1] = wy1 * wz1 * ww1;

            const float wxv[2] = {wx0, wx1};
            const int axv[2] = {tlx, brx};
            const int ayv[2] = {tly, bry};
            const int azv[2] = {tlz, brz};
            const int awv[2] = {tlw, brw};

            // enumerate the 16 corners in the bit-exact (iy,ix,iz,iw) order
            float wk[16];
            int   ofs[16];
            #pragma unroll
            for (int iy = 0; iy < 2; ++iy)
              #pragma unroll
              for (int ix = 0; ix < 2; ++ix) {
                const int base1 = (ayv[iy] * 64 + axv[ix]) * 32;
                #pragma unroll
                for (int iz = 0; iz < 2; ++iz) {
                  const int base0 = (base1 + azv[iz]) * 32;
                  #pragma unroll
                  for (int iw = 0; iw < 2; ++iw) {
                    const int kk = ((iy * 2 + ix) * 2 + iz) * 2 + iw;
                    wk[kk]  = wxv[ix] * cw[iy][iz][iw];
                    ofs[kk] = (base0 + awv[iw]) * 64 + l * 16;  // byte offset
                  }
                }
              }

            // two batches of 8 deep loads (bounded reg pressure, good ILP)
            #pragma unroll
            for (int h8 = 0; h8 < 2; ++h8) {
                float4 cv[8];
                #pragma unroll
                for (int c = 0; c < 8; ++c)
                    cv[c] = *reinterpret_cast<const float4*>(
                        reinterpret_cast<const char*>(grid) + ofs[h8 * 8 + c]);
                #pragma unroll
                for (int c = 0; c < 8; ++c) {
                    const float w = wk[h8 * 8 + c];
                    acc.x += w * cv[c].x;
                    acc.y += w * cv[c].y;
                    acc.z += w * cv[c].z;
                    acc.w += w * cv[c].w;
                }
            }
        }
        featS[(4 * l + 0) * FEAT_PITCH + pl] = acc.x;
        featS[(4 * l + 1) * FEAT_PITCH + pl] = acc.y;
        featS[(4 * l + 2) * FEAT_PITCH + pl] = acc.z;
        featS[(4 * l + 3) * FEAT_PITCH + pl] = acc.w;
    }
    __syncthreads();

    // ---- phase 2: MLP GEMM. thread = (pg: 8 pts, g: 8 js)
    const int g  = t & 7;          // j-group: js g*8 .. g*8+7
    const int pg = t >> 3;         // pt-group: pts pg*8 .. pg*8+7

    float h[8][8];                 // [pt][j]
    #pragma unroll
    for (int p = 0; p < 8; ++p)
        #pragma unroll
        for (int j = 0; j < 8; ++j)
            h[p][j] = b1s[g * 8 + j];

    #pragma unroll
    for (int i = 0; i < 16; ++i) {
        const float4 wA = *reinterpret_cast<const float4*>(&w1s[i * 64 + g * 8]);
        const float4 wB = *reinterpret_cast<const float4*>(&w1s[i * 64 + g * 8 + 4]);
        const float4 fA = *reinterpret_cast<const float4*>(&featS[i * FEAT_PITCH + pg * 8]);
        const float4 fB = *reinterpret_cast<const float4*>(&featS[i * FEAT_PITCH + pg * 8 + 4]);
        const float fv[8] = {fA.x, fA.y, fA.z, fA.w, fB.x, fB.y, fB.z, fB.w};
        const float wv[8] = {wA.x, wA.y, wA.z, wA.w, wB.x, wB.y, wB.z, wB.w};
        #pragma unroll
        for (int p = 0; p < 8; ++p)
            #pragma unroll
            for (int j = 0; j < 8; ++j)
                h[p][j] += fv[p] * wv[j];
    }

    float o[8][3];
    #pragma unroll
    for (int p = 0; p < 8; ++p) { o[p][0] = 0.f; o[p][1] = 0.f; o[p][2] = 0.f; }

    #pragma unroll
    for (int j = 0; j < 8; ++j) {
        const float w20 = w2s[(g * 8 + j) * 3 + 0];
        const float w21 = w2s[(g * 8 + j) * 3 + 1];
        const float w22 = w2s[(g * 8 + j) * 3 + 2];
        #pragma unroll
        for (int p = 0; p < 8; ++p) {
            const float hv = (h[p][j] >= 0.0f) ? h[p][j] : 0.01f * h[p][j];
            o[p][0] += hv * w20;
            o[p][1] += hv * w21;
            o[p][2] += hv * w22;
        }
    }

    // butterfly allreduce across the 8 j-groups (lanes t^1, t^2, t^4)
    #pragma unroll
    for (int m = 1; m < 8; m <<= 1)
        #pragma unroll
        for (int p = 0; p < 8; ++p) {
            o[p][0] += __shfl_xor(o[p][0], m);
            o[p][1] += __shfl_xor(o[p][1], m);
            o[p][2] += __shfl_xor(o[p][2], m);
        }

    // lane g finalizes point pg*8+g
    float og[3];
    #pragma unroll
    for (int p = 0; p < 8; ++p)
        if (p == g) { og[0] = o[p][0]; og[1] = o[p][1]; og[2] = o[p][2]; }

    const int pl = pg * 8 + g;
    const int gp = base + pl;
    if (gp < N) {
        const int op = SORTED ? (int)idx[gp] : gp;
        float* dst = out + (size_t)op * 3;
        #pragma unroll
        for (int c = 0; c < 3; ++c) {
            const float v = og[c] + b2s[c];
            dst[c] = 255.0f / (1.0f + expf(-v));
        }
    }
}

extern "C" void kernel_launch(void* const* d_in, const int* in_sizes, int n_in,
                              void* d_out, int out_size, void* d_ws, size_t ws_size,
                              hipStream_t stream) {
    const float* x    = (const float*)d_in[0];
    const float* grid = (const float*)d_in[1];
    const float* w1   = (const float*)d_in[2];
    const float* b1   = (const float*)d_in[3];
    const float* w2   = (const float*)d_in[4];
    const float* b2   = (const float*)d_in[5];
    float* out = (float*)d_out;

    const int N = in_sizes[0] / 4;               // x is [N,4]
    const int nblk = (N + 255) / 256;

    const size_t xs_bytes   = (size_t)N * 16;
    const size_t idx_bytes  = (size_t)N * 4;
    const size_t hist_bytes = (size_t)NBUCKET * 4;
    const size_t part_bytes = (size_t)SCAN_BLOCKS * 4;
    const size_t need = xs_bytes + idx_bytes + hist_bytes + part_bytes;

    if (ws_size >= need) {
        char* ws = (char*)d_ws;
        float4*   xs      = (float4*)ws;
        unsigned* idx     = (unsigned*)(ws + xs_bytes);
        unsigned* hist    = (unsigned*)(ws + xs_bytes + idx_bytes);
        unsigned* partial = (unsigned*)(ws + xs_bytes + idx_bytes + hist_bytes);
        const float4* x4 = (const float4*)x;

        k_zero   <<<NBUCKET / 1024, 1024, 0, stream>>>(hist);
        k_hist   <<<nblk, 256, 0, stream>>>(x4, hist, N);
        k_scanA  <<<SCAN_BLOCKS, 1024, 0, stream>>>(hist, partial);
        k_scanB  <<<1, SCAN_BLOCKS, 0, stream>>>(partial);
        k_scanC  <<<SCAN_BLOCKS, 1024, 0, stream>>>(hist, partial);
        k_scatter<<<nblk, 256, 0, stream>>>(x4, hist, xs, idx, N);
        gridnet_main<true><<<nblk, 256, 0, stream>>>(
            xs, idx, grid, w1, b1, w2, b2, out, N, nblk);
    } else {
        gridnet_main<false><<<nblk, 256, 0, stream>>>(
            (const float4*)x, nullptr, grid, w1, b1, w2, b2, out, N, nblk);
    }
}